// Round 2
// baseline (925.174 us; speedup 1.0000x reference)
//
#include <hip/hip_runtime.h>
#include <math.h>

#define BB    8
#define NB_CH 2                  // batch images per chunk
#define HH    112
#define WWI   112
#define CC    192
#define NH    6
#define HD    32
#define WSZ   7
#define WN    16                 // windows per side (112/7)
#define NPIX  (HH*WWI)           // 12544
#define MCH   (NB_CH*NPIX)       // 25088 rows per chunk
#define QKV_N 576

// ---------------------------------------------------------------------------
// GEMM: C[m,n] = sum_k A[m,k]*B[n,k] (+ bias[n]).  A: MxK row-major,
// B: NxK row-major (i.e. C = A @ B^T).  BM=BN=64, BK=16, 4x4 per thread.
// ---------------------------------------------------------------------------
__global__ __launch_bounds__(256) void gemm_nt(const float* __restrict__ A,
                                               const float* __restrict__ B,
                                               const float* __restrict__ bias,
                                               float* __restrict__ C,
                                               int M, int N, int K) {
    __shared__ float As[16][68];   // [k][m], padded (272B rows, 16B-aligned)
    __shared__ float Bs[16][68];   // [k][n]
    const int tid = threadIdx.x;
    const int bn  = blockIdx.x * 64;
    const int bm  = blockIdx.y * 64;
    const int lr  = tid >> 2;          // 0..63 (row within tile)
    const int lk  = (tid & 3) << 2;    // 0,4,8,12 (k offset)
    const int tx  = tid & 15;
    const int ty  = tid >> 4;
    const float* Ap = A + (size_t)(bm + lr) * K + lk;
    const float* Bp = B + (size_t)(bn + lr) * K + lk;
    float acc[4][4] = {{0.f,0.f,0.f,0.f},{0.f,0.f,0.f,0.f},
                       {0.f,0.f,0.f,0.f},{0.f,0.f,0.f,0.f}};
    for (int k0 = 0; k0 < K; k0 += 16) {
        float4 av = *(const float4*)(Ap + k0);
        float4 bv = *(const float4*)(Bp + k0);
        __syncthreads();
        As[lk+0][lr] = av.x; As[lk+1][lr] = av.y;
        As[lk+2][lr] = av.z; As[lk+3][lr] = av.w;
        Bs[lk+0][lr] = bv.x; Bs[lk+1][lr] = bv.y;
        Bs[lk+2][lr] = bv.z; Bs[lk+3][lr] = bv.w;
        __syncthreads();
        #pragma unroll
        for (int kk = 0; kk < 16; ++kk) {
            float4 a = *(const float4*)&As[kk][ty << 2];
            float4 b = *(const float4*)&Bs[kk][tx << 2];
            acc[0][0] += a.x*b.x; acc[0][1] += a.x*b.y; acc[0][2] += a.x*b.z; acc[0][3] += a.x*b.w;
            acc[1][0] += a.y*b.x; acc[1][1] += a.y*b.y; acc[1][2] += a.y*b.z; acc[1][3] += a.y*b.w;
            acc[2][0] += a.z*b.x; acc[2][1] += a.z*b.y; acc[2][2] += a.z*b.z; acc[2][3] += a.z*b.w;
            acc[3][0] += a.w*b.x; acc[3][1] += a.w*b.y; acc[3][2] += a.w*b.z; acc[3][3] += a.w*b.w;
        }
    }
    float4 bv4 = make_float4(0.f, 0.f, 0.f, 0.f);
    if (bias) bv4 = *(const float4*)&bias[bn + (tx << 2)];
    #pragma unroll
    for (int i = 0; i < 4; ++i) {
        float4 o;
        o.x = acc[i][0] + bv4.x; o.y = acc[i][1] + bv4.y;
        o.z = acc[i][2] + bv4.z; o.w = acc[i][3] + bv4.w;
        *(float4*)&C[(size_t)(bm + (ty << 2) + i) * N + bn + (tx << 2)] = o;
    }
}

// ---------------------------------------------------------------------------
// K2: 7x7 mean pool -> leaky_relu -> 54-ch transform -> affine -> sample grid.
// One 64-thread block per (b, wy, wx).  Grid covers ALL batches.
// ---------------------------------------------------------------------------
__global__ __launch_bounds__(64) void pool_grid(const float* __restrict__ x,
                                                const float* __restrict__ tw,
                                                const float* __restrict__ tb,
                                                float* __restrict__ grid) {
    const int blk = blockIdx.x;            // b*256 + wy*16 + wx
    const int b  = blk >> 8;
    const int wy = (blk >> 4) & 15;
    const int wx = blk & 15;
    const int tid = threadIdx.x;
    __shared__ float pooled[CC];
    __shared__ float samp[54];

    for (int c = tid; c < CC; c += 64) {
        float s = 0.f;
        #pragma unroll
        for (int iy = 0; iy < WSZ; ++iy) {
            int y = wy * WSZ + iy;
            #pragma unroll
            for (int ix = 0; ix < WSZ; ++ix) {
                int xx = wx * WSZ + ix;
                s += x[((size_t)b * NPIX + y * WWI + xx) * CC + c];
            }
        }
        s *= (1.f / 49.f);
        pooled[c] = (s >= 0.f) ? s : 0.01f * s;   // leaky_relu(0.01)
    }
    __syncthreads();
    if (tid < 54) {
        float s = tb[tid];
        const float* w = tw + tid * CC;
        for (int c = 0; c < CC; ++c) s += pooled[c] * w[c];
        samp[tid] = s;
    }
    __syncthreads();
    // 6 heads x 49 positions
    for (int it = tid; it < NH * 49; it += 64) {
        const int n = it / 49;
        const int p = it % 49;
        const int iy = p / WSZ, ix = p % WSZ;
        const float* sp = &samp[n * 9];
        const float off0 = sp[0] * (1.f / 16.f);
        const float off1 = sp[1] * (1.f / 16.f);
        const float sc0 = sp[2] + 1.f, sc1 = sp[3] + 1.f;
        const float sh0 = sp[4], sh1 = sp[5];
        const float pc0 = sp[6], pc1 = sp[7];
        const float rot = sp[8];
        const float cr = cosf(rot), sr = sinf(rot);
        // basic = (rot @ shear) @ scale
        const float a00 = (cr + sr * sh1) * sc0;
        const float a01 = (cr * sh0 + sr) * sc1;
        const float a10 = (-sr + cr * sh1) * sc0;
        const float a11 = (-sr * sh0 + cr) * sc1;
        const float wcx = (float)(ix - 3) * (2.f / 111.f);
        const float wcy = (float)(iy - 3) * (2.f / 111.f);
        const float t0 = a00 * wcx + a01 * wcy + off0;
        const float t1 = a10 * wcx + a11 * wcy + off1;
        const float t2 = pc0 * wcx + pc1 * wcy + 1.f;
        const float den = (t2 == 0.f) ? 1e-6f : t2;
        const float cenx = -1.f + (2.f / 111.f) * (float)(7 * wx + 3);
        const float ceny = -1.f + (2.f / 111.f) * (float)(7 * wy + 3);
        const float cx = t0 / den + cenx;
        const float cy = t1 / den + ceny;
        const int bn = b * NH + n;
        const int y = wy * WSZ + iy, xx = wx * WSZ + ix;
        const size_t gi = (((size_t)bn * HH + y) * WWI + xx) * 2;
        grid[gi]     = cx;
        grid[gi + 1] = cy;
    }
}

// ---------------------------------------------------------------------------
// K3: fused window attention.  One 256-thread block per (b_local, wy, wx, head).
// qkv/aout are CHUNK-local (NB_CH batch images); grid is full (b0 offset).
// ---------------------------------------------------------------------------
__device__ __forceinline__ float dot32(const float4* a, const float4* b) {
    float s = 0.f;
    #pragma unroll
    for (int j = 0; j < 8; ++j) {
        float4 av = a[j], bv = b[j];
        s += av.x * bv.x + av.y * bv.y + av.z * bv.z + av.w * bv.w;
    }
    return s;
}

__global__ __launch_bounds__(256) void attn_win(const float* __restrict__ qkv,
                                                const float* __restrict__ grid,
                                                const float* __restrict__ rph,
                                                const float* __restrict__ rpw,
                                                float* __restrict__ aout,
                                                int b0) {
    const int id = blockIdx.x;            // ((bl*16+wy)*16+wx)*6 + n
    const int n  = id % NH;
    const int wxy = id / NH;
    const int wx = wxy % WN;
    const int wy = (wxy / WN) % WN;
    const int bl = wxy / (WN * WN);       // batch image within chunk
    const int tid = threadIdx.x;
    const int bng = (b0 + bl) * NH + n;   // global (b,head) for grid

    __shared__ float qs[49][36];
    __shared__ float ks[49][36];
    __shared__ float vs[49][36];
    __shared__ float relh[49][8];
    __shared__ float relw[49][8];
    __shared__ float att[49][52];
    __shared__ float gx[49], gy[49];

    if (tid < 49) {
        const int y = wy * WSZ + tid / WSZ, xx = wx * WSZ + tid % WSZ;
        const size_t gi = (((size_t)bng * HH + y) * WWI + xx) * 2;
        gx[tid] = grid[gi];
        gy[tid] = grid[gi + 1];
    }
    // qs (scaled)
    for (int i = tid; i < 49 * 32; i += 256) {
        const int p = i >> 5, d = i & 31;
        const int y = wy * WSZ + p / WSZ, xx = wx * WSZ + p % WSZ;
        qs[p][d] = qkv[((size_t)bl * NPIX + y * WWI + xx) * QKV_N + n * HD + d]
                   * 0.17677669529663687f;   // 32^-0.5
    }
    __syncthreads();
    // bilinear sample k_sel, v_sel (zero padding)
    for (int i = tid; i < 49 * 32; i += 256) {
        const int p = i >> 5, d = i & 31;
        const float X = (gx[p] + 1.f) * 0.5f * (float)(WWI - 1);
        const float Y = (gy[p] + 1.f) * 0.5f * (float)(HH - 1);
        const float x0 = floorf(X), y0 = floorf(Y);
        const float fx = X - x0, fy = Y - y0;
        float ka = 0.f, va = 0.f;
        #pragma unroll
        for (int c = 0; c < 4; ++c) {
            const float xc = x0 + (float)(c & 1);
            const float yc = y0 + (float)(c >> 1);
            const float wgt = ((c & 1) ? fx : 1.f - fx) * ((c >> 1) ? fy : 1.f - fy);
            const bool valid = (xc >= 0.f) && (xc <= (float)(WWI - 1)) &&
                               (yc >= 0.f) && (yc <= (float)(HH - 1));
            const float xcl = fminf(fmaxf(xc, 0.f), (float)(WWI - 1));
            const float ycl = fminf(fmaxf(yc, 0.f), (float)(HH - 1));
            const int xi = (int)xcl, yi = (int)ycl;
            const float wv = valid ? wgt : 0.f;
            const size_t base = ((size_t)bl * NPIX + yi * WWI + xi) * QKV_N + CC + n * HD + d;
            ka += qkv[base] * wv;          // k
            va += qkv[base + CC] * wv;     // v
        }
        ks[p][d] = ka;
        vs[p][d] = va;
    }
    // rel-pos tables (only need qs)
    for (int i = tid; i < 49 * 7; i += 256) {
        const int q = i / 7, kk = i % 7;
        const int qy = q / WSZ, qx = q % WSZ;
        const float* Rh = rph + (size_t)(qy - kk + 6) * HD;
        const float* Rw = rpw + (size_t)(qx - kk + 6) * HD;
        float sh = 0.f, sw = 0.f;
        #pragma unroll
        for (int d = 0; d < HD; ++d) {
            const float qv = qs[q][d];
            sh += qv * Rh[d];
            sw += qv * Rw[d];
        }
        relh[q][kk] = sh;
        relw[q][kk] = sw;
    }
    __syncthreads();
    // dots: task = (q, kh): 7 keys sharing relh
    for (int i = tid; i < 49 * 7; i += 256) {
        const int q = i / 7, kh = i % 7;
        float4 qv[8];
        #pragma unroll
        for (int j = 0; j < 8; ++j) qv[j] = *(const float4*)&qs[q][j << 2];
        const float rh = relh[q][kh];
        #pragma unroll
        for (int t = 0; t < 7; ++t) {
            const int k = kh * 7 + t;
            const float s = dot32(qv, (const float4*)&ks[k][0]);
            att[q][k] = s + rh + relw[q][t];
        }
    }
    __syncthreads();
    // softmax per row, 4 lanes per row
    {
        const int grp = tid >> 2, l = tid & 3;
        if (grp < 49) {
            float mx = -1e30f;
            for (int k = l; k < 49; k += 4) mx = fmaxf(mx, att[grp][k]);
            mx = fmaxf(mx, __shfl_xor(mx, 1, 4));
            mx = fmaxf(mx, __shfl_xor(mx, 2, 4));
            float s = 0.f;
            for (int k = l; k < 49; k += 4) {
                const float e = expf(att[grp][k] - mx);
                att[grp][k] = e;
                s += e;
            }
            s += __shfl_xor(s, 1, 4);
            s += __shfl_xor(s, 2, 4);
            const float inv = 1.f / s;
            for (int k = l; k < 49; k += 4) att[grp][k] *= inv;
        }
    }
    __syncthreads();
    // out = attn @ v_sel ; write chunk-local [pixel][192]
    for (int i = tid; i < 49 * 32; i += 256) {
        const int q = i >> 5, d = i & 31;
        float s = 0.f;
        #pragma unroll
        for (int k = 0; k < 49; ++k) s += att[q][k] * vs[k][d];
        const int y = wy * WSZ + q / WSZ, xx = wx * WSZ + q % WSZ;
        aout[((size_t)bl * NPIX + y * WWI + xx) * CC + n * HD + d] = s;
    }
}

// ---------------------------------------------------------------------------
extern "C" void kernel_launch(void* const* d_in, const int* in_sizes, int n_in,
                              void* d_out, int out_size, void* d_ws, size_t ws_size,
                              hipStream_t stream) {
    (void)in_sizes; (void)n_in; (void)out_size; (void)ws_size;
    const float* x     = (const float*)d_in[0];
    const float* qkv_w = (const float*)d_in[1];
    const float* tw    = (const float*)d_in[2];
    const float* tb    = (const float*)d_in[3];
    const float* pw    = (const float*)d_in[4];
    const float* pb    = (const float*)d_in[5];
    const float* rph   = (const float*)d_in[6];
    const float* rpw   = (const float*)d_in[7];
    float* out = (float*)d_out;

    // ws layout (chunked; peak ~82 MB):
    float* ws   = (float*)d_ws;
    float* qkv  = ws;                                   // MCH*576       (57.8 MB)
    float* aout = qkv + (size_t)MCH * QKV_N;            // MCH*192       (19.3 MB)
    float* grid = aout + (size_t)MCH * CC;              // 48*112*112*2  ( 4.8 MB)

    // K2 once: pooled/transform/affine/grid for all batches
    pool_grid<<<dim3(BB * WN * WN), 64, 0, stream>>>(x, tw, tb, grid);

    for (int b0 = 0; b0 < BB; b0 += NB_CH) {
        const float* xc  = x   + (size_t)b0 * NPIX * CC;
        float*       oc  = out + (size_t)b0 * NPIX * CC;
        // K1: qkv_chunk = x_chunk @ qkv_w^T
        gemm_nt<<<dim3(QKV_N / 64, MCH / 64), 256, 0, stream>>>(
            xc, qkv_w, nullptr, qkv, MCH, QKV_N, CC);
        // K3: fused window attention for this chunk
        attn_win<<<dim3(NB_CH * WN * WN * NH), 256, 0, stream>>>(
            qkv, grid, rph, rpw, aout, b0);
        // K4: out_chunk = aout @ proj_w^T + proj_b
        gemm_nt<<<dim3(CC / 64, MCH / 64), 256, 0, stream>>>(
            aout, pw, pb, oc, MCH, CC, CC);
    }
}

// Round 4
// 671.043 us; speedup vs baseline: 1.3787x; 1.3787x over previous
//
#include <hip/hip_runtime.h>
#include <math.h>

#define BB    8
#define NB_CH 2                  // batch images per chunk
#define HH    112
#define WWI   112
#define CC    192
#define NH    6
#define HD    32
#define WSZ   7
#define WN    16                 // windows per side (112/7)
#define NPIX  (HH*WWI)           // 12544
#define MCH   (NB_CH*NPIX)       // 25088 rows per chunk
#define QKV_N 576

typedef __attribute__((ext_vector_type(8))) short  bf16x8;
typedef __attribute__((ext_vector_type(4))) short  s16x4;
typedef __attribute__((ext_vector_type(4))) float  f32x4;

// RTNE float -> bf16 split: f ≈ hi + lo, both bf16. Residual captured to ~2^-17.
__device__ __forceinline__ void split_bf16(float f, short& hi, short& lo) {
    unsigned u  = __builtin_bit_cast(unsigned, f);
    unsigned rh = (u + 0x7fffu + ((u >> 16) & 1u)) & 0xffff0000u;
    hi = (short)(rh >> 16);
    float fh = __builtin_bit_cast(float, rh);
    float res = f - fh;                       // exact in fp32
    unsigned v = __builtin_bit_cast(unsigned, res);
    lo = (short)((v + 0x7fffu + ((v >> 16) & 1u)) >> 16);
}

__device__ __forceinline__ void split4(const float4 f, s16x4& h, s16x4& l) {
    short h0, h1, h2, h3, l0, l1, l2, l3;
    split_bf16(f.x, h0, l0);
    split_bf16(f.y, h1, l1);
    split_bf16(f.z, h2, l2);
    split_bf16(f.w, h3, l3);
    h = (s16x4){h0, h1, h2, h3};
    l = (s16x4){l0, l1, l2, l3};
}

// ---------------------------------------------------------------------------
// MFMA GEMM (split-bf16, fp32-class accuracy): C[m,n] = sum_k A[m,k]*B[n,k]
// (+bias[n]).  A: MxK fp32 row-major, B: NxK fp32 row-major (C = A @ B^T).
// BM=128, BN=64, BK=32.  4 waves, each owns 64x32 (4x2 frags of 16x16).
// Requires M%128==0, N%64==0, K%32==0.
// ---------------------------------------------------------------------------
__global__ __launch_bounds__(256) void gemm_mfma(const float* __restrict__ A,
                                                 const float* __restrict__ B,
                                                 const float* __restrict__ bias,
                                                 float* __restrict__ C,
                                                 int M, int N, int K) {
    __shared__ short Ah[128][40];   // 80B rows (pad 32->40 bf16)
    __shared__ short Al[128][40];
    __shared__ short Bh[64][40];
    __shared__ short Bl[64][40];
    const int tid  = threadIdx.x;
    const int bn   = blockIdx.x * 64;
    const int bm   = blockIdx.y * 128;
    const int lane = tid & 63;
    const int wave = tid >> 6;
    const int wm   = wave & 1;          // m-half (64 rows)
    const int wn   = wave >> 1;         // n-half (32 cols)
    const int fr   = lane & 15;         // fragment row/col
    const int ko   = (lane >> 4) * 8;   // fragment k offset

    f32x4 acc[4][2] = {};

    for (int k0 = 0; k0 < K; k0 += 32) {
        float4 av[4], bv[2];
        #pragma unroll
        for (int i = 0; i < 4; ++i) {
            const int idx = tid + 256 * i, row = idx >> 3, c4 = idx & 7;
            av[i] = *(const float4*)(A + (size_t)(bm + row) * K + k0 + c4 * 4);
        }
        #pragma unroll
        for (int i = 0; i < 2; ++i) {
            const int idx = tid + 256 * i, row = idx >> 3, c4 = idx & 7;
            bv[i] = *(const float4*)(B + (size_t)(bn + row) * K + k0 + c4 * 4);
        }
        __syncthreads();
        #pragma unroll
        for (int i = 0; i < 4; ++i) {
            const int idx = tid + 256 * i, row = idx >> 3, c4 = idx & 7;
            s16x4 h, l;
            split4(av[i], h, l);
            *(s16x4*)&Ah[row][c4 * 4] = h;
            *(s16x4*)&Al[row][c4 * 4] = l;
        }
        #pragma unroll
        for (int i = 0; i < 2; ++i) {
            const int idx = tid + 256 * i, row = idx >> 3, c4 = idx & 7;
            s16x4 h, l;
            split4(bv[i], h, l);
            *(s16x4*)&Bh[row][c4 * 4] = h;
            *(s16x4*)&Bl[row][c4 * 4] = l;
        }
        __syncthreads();

        bf16x8 ah[4], al[4], bh[2], bl[2];
        #pragma unroll
        for (int mt = 0; mt < 4; ++mt) {
            const int m = wm * 64 + mt * 16 + fr;
            ah[mt] = *(const bf16x8*)&Ah[m][ko];
            al[mt] = *(const bf16x8*)&Al[m][ko];
        }
        #pragma unroll
        for (int nt = 0; nt < 2; ++nt) {
            const int n = wn * 32 + nt * 16 + fr;
            bh[nt] = *(const bf16x8*)&Bh[n][ko];
            bl[nt] = *(const bf16x8*)&Bl[n][ko];
        }
        #pragma unroll
        for (int mt = 0; mt < 4; ++mt) {
            #pragma unroll
            for (int nt = 0; nt < 2; ++nt) {
                acc[mt][nt] = __builtin_amdgcn_mfma_f32_16x16x32_bf16(
                    al[mt], bh[nt], acc[mt][nt], 0, 0, 0);
                acc[mt][nt] = __builtin_amdgcn_mfma_f32_16x16x32_bf16(
                    ah[mt], bl[nt], acc[mt][nt], 0, 0, 0);
                acc[mt][nt] = __builtin_amdgcn_mfma_f32_16x16x32_bf16(
                    ah[mt], bh[nt], acc[mt][nt], 0, 0, 0);
            }
        }
    }

    const int crow0 = bm + wm * 64 + (lane >> 4) * 4;
    const int ccol0 = bn + wn * 32 + fr;
    #pragma unroll
    for (int nt = 0; nt < 2; ++nt) {
        const int cc = ccol0 + nt * 16;
        const float bb = bias ? bias[cc] : 0.f;
        #pragma unroll
        for (int mt = 0; mt < 4; ++mt) {
            #pragma unroll
            for (int i = 0; i < 4; ++i) {
                C[(size_t)(crow0 + mt * 16 + i) * N + cc] = acc[mt][nt][i] + bb;
            }
        }
    }
}

// ---------------------------------------------------------------------------
// K2: 7x7 mean pool -> leaky_relu -> 54-ch transform -> affine -> sample grid.
// One 64-thread block per (b, wy, wx).  Grid covers ALL batches.
// ---------------------------------------------------------------------------
__global__ __launch_bounds__(64) void pool_grid(const float* __restrict__ x,
                                                const float* __restrict__ tw,
                                                const float* __restrict__ tb,
                                                float* __restrict__ grid) {
    const int blk = blockIdx.x;            // b*256 + wy*16 + wx
    const int b  = blk >> 8;
    const int wy = (blk >> 4) & 15;
    const int wx = blk & 15;
    const int tid = threadIdx.x;
    __shared__ float pooled[CC];
    __shared__ float samp[54];

    for (int c = tid; c < CC; c += 64) {
        float s = 0.f;
        #pragma unroll
        for (int iy = 0; iy < WSZ; ++iy) {
            int y = wy * WSZ + iy;
            #pragma unroll
            for (int ix = 0; ix < WSZ; ++ix) {
                int xx = wx * WSZ + ix;
                s += x[((size_t)b * NPIX + y * WWI + xx) * CC + c];
            }
        }
        s *= (1.f / 49.f);
        pooled[c] = (s >= 0.f) ? s : 0.01f * s;   // leaky_relu(0.01)
    }
    __syncthreads();
    if (tid < 54) {
        float s = tb[tid];
        const float* w = tw + tid * CC;
        for (int c = 0; c < CC; ++c) s += pooled[c] * w[c];
        samp[tid] = s;
    }
    __syncthreads();
    // 6 heads x 49 positions
    for (int it = tid; it < NH * 49; it += 64) {
        const int n = it / 49;
        const int p = it % 49;
        const int iy = p / WSZ, ix = p % WSZ;
        const float* sp = &samp[n * 9];
        const float off0 = sp[0] * (1.f / 16.f);
        const float off1 = sp[1] * (1.f / 16.f);
        const float sc0 = sp[2] + 1.f, sc1 = sp[3] + 1.f;
        const float sh0 = sp[4], sh1 = sp[5];
        const float pc0 = sp[6], pc1 = sp[7];
        const float rot = sp[8];
        const float cr = cosf(rot), sr = sinf(rot);
        // basic = (rot @ shear) @ scale
        const float a00 = (cr + sr * sh1) * sc0;
        const float a01 = (cr * sh0 + sr) * sc1;
        const float a10 = (-sr + cr * sh1) * sc0;
        const float a11 = (-sr * sh0 + cr) * sc1;
        const float wcx = (float)(ix - 3) * (2.f / 111.f);
        const float wcy = (float)(iy - 3) * (2.f / 111.f);
        const float t0 = a00 * wcx + a01 * wcy + off0;
        const float t1 = a10 * wcx + a11 * wcy + off1;
        const float t2 = pc0 * wcx + pc1 * wcy + 1.f;
        const float den = (t2 == 0.f) ? 1e-6f : t2;
        const float cenx = -1.f + (2.f / 111.f) * (float)(7 * wx + 3);
        const float ceny = -1.f + (2.f / 111.f) * (float)(7 * wy + 3);
        const float cx = t0 / den + cenx;
        const float cy = t1 / den + ceny;
        const int bn = b * NH + n;
        const int y = wy * WSZ + iy, xx = wx * WSZ + ix;
        const size_t gi = (((size_t)bn * HH + y) * WWI + xx) * 2;
        grid[gi]     = cx;
        grid[gi + 1] = cy;
    }
}

// ---------------------------------------------------------------------------
// K3: fused window attention.  One 256-thread block per (b_local, wy, wx, head).
// qkv/aout are CHUNK-local (NB_CH batch images); grid is full (b0 offset).
// ---------------------------------------------------------------------------
__device__ __forceinline__ float dot32(const float4* a, const float4* b) {
    float s = 0.f;
    #pragma unroll
    for (int j = 0; j < 8; ++j) {
        float4 av = a[j], bv = b[j];
        s += av.x * bv.x + av.y * bv.y + av.z * bv.z + av.w * bv.w;
    }
    return s;
}

__global__ __launch_bounds__(256) void attn_win(const float* __restrict__ qkv,
                                                const float* __restrict__ grid,
                                                const float* __restrict__ rph,
                                                const float* __restrict__ rpw,
                                                float* __restrict__ aout,
                                                int b0) {
    const int id = blockIdx.x;            // ((bl*16+wy)*16+wx)*6 + n
    const int n  = id % NH;
    const int wxy = id / NH;
    const int wx = wxy % WN;
    const int wy = (wxy / WN) % WN;
    const int bl = wxy / (WN * WN);       // batch image within chunk
    const int tid = threadIdx.x;
    const int bng = (b0 + bl) * NH + n;   // global (b,head) for grid

    __shared__ float qs[49][36];
    __shared__ float ks[49][36];
    __shared__ float vs[49][36];
    __shared__ float relh[49][8];
    __shared__ float relw[49][8];
    __shared__ float att[49][52];
    __shared__ float gx[49], gy[49];

    if (tid < 49) {
        const int y = wy * WSZ + tid / WSZ, xx = wx * WSZ + tid % WSZ;
        const size_t gi = (((size_t)bng * HH + y) * WWI + xx) * 2;
        gx[tid] = grid[gi];
        gy[tid] = grid[gi + 1];
    }
    // qs (scaled)
    for (int i = tid; i < 49 * 32; i += 256) {
        const int p = i >> 5, d = i & 31;
        const int y = wy * WSZ + p / WSZ, xx = wx * WSZ + p % WSZ;
        qs[p][d] = qkv[((size_t)bl * NPIX + y * WWI + xx) * QKV_N + n * HD + d]
                   * 0.17677669529663687f;   // 32^-0.5
    }
    __syncthreads();
    // bilinear sample k_sel, v_sel (zero padding)
    for (int i = tid; i < 49 * 32; i += 256) {
        const int p = i >> 5, d = i & 31;
        const float X = (gx[p] + 1.f) * 0.5f * (float)(WWI - 1);
        const float Y = (gy[p] + 1.f) * 0.5f * (float)(HH - 1);
        const float x0 = floorf(X), y0 = floorf(Y);
        const float fx = X - x0, fy = Y - y0;
        float ka = 0.f, va = 0.f;
        #pragma unroll
        for (int c = 0; c < 4; ++c) {
            const float xc = x0 + (float)(c & 1);
            const float yc = y0 + (float)(c >> 1);
            const float wgt = ((c & 1) ? fx : 1.f - fx) * ((c >> 1) ? fy : 1.f - fy);
            const bool valid = (xc >= 0.f) && (xc <= (float)(WWI - 1)) &&
                               (yc >= 0.f) && (yc <= (float)(HH - 1));
            const float xcl = fminf(fmaxf(xc, 0.f), (float)(WWI - 1));
            const float ycl = fminf(fmaxf(yc, 0.f), (float)(HH - 1));
            const int xi = (int)xcl, yi = (int)ycl;
            const float wv = valid ? wgt : 0.f;
            const size_t base = ((size_t)bl * NPIX + yi * WWI + xi) * QKV_N + CC + n * HD + d;
            ka += qkv[base] * wv;          // k
            va += qkv[base + CC] * wv;     // v
        }
        ks[p][d] = ka;
        vs[p][d] = va;
    }
    // rel-pos tables (only need qs)
    for (int i = tid; i < 49 * 7; i += 256) {
        const int q = i / 7, kk = i % 7;
        const int qy = q / WSZ, qx = q % WSZ;
        const float* Rh = rph + (size_t)(qy - kk + 6) * HD;
        const float* Rw = rpw + (size_t)(qx - kk + 6) * HD;
        float sh = 0.f, sw = 0.f;
        #pragma unroll
        for (int d = 0; d < HD; ++d) {
            const float qv = qs[q][d];
            sh += qv * Rh[d];
            sw += qv * Rw[d];
        }
        relh[q][kk] = sh;
        relw[q][kk] = sw;
    }
    __syncthreads();
    // dots: task = (q, kh): 7 keys sharing relh
    for (int i = tid; i < 49 * 7; i += 256) {
        const int q = i / 7, kh = i % 7;
        float4 qv[8];
        #pragma unroll
        for (int j = 0; j < 8; ++j) qv[j] = *(const float4*)&qs[q][j << 2];
        const float rh = relh[q][kh];
        #pragma unroll
        for (int t = 0; t < 7; ++t) {
            const int k = kh * 7 + t;
            const float s = dot32(qv, (const float4*)&ks[k][0]);
            att[q][k] = s + rh + relw[q][t];
        }
    }
    __syncthreads();
    // softmax per row, 4 lanes per row
    {
        const int grp = tid >> 2, l = tid & 3;
        if (grp < 49) {
            float mx = -1e30f;
            for (int k = l; k < 49; k += 4) mx = fmaxf(mx, att[grp][k]);
            mx = fmaxf(mx, __shfl_xor(mx, 1, 4));
            mx = fmaxf(mx, __shfl_xor(mx, 2, 4));
            float s = 0.f;
            for (int k = l; k < 49; k += 4) {
                const float e = expf(att[grp][k] - mx);
                att[grp][k] = e;
                s += e;
            }
            s += __shfl_xor(s, 1, 4);
            s += __shfl_xor(s, 2, 4);
            const float inv = 1.f / s;
            for (int k = l; k < 49; k += 4) att[grp][k] *= inv;
        }
    }
    __syncthreads();
    // out = attn @ v_sel ; write chunk-local [pixel][192]
    for (int i = tid; i < 49 * 32; i += 256) {
        const int q = i >> 5, d = i & 31;
        float s = 0.f;
        #pragma unroll
        for (int k = 0; k < 49; ++k) s += att[q][k] * vs[k][d];
        const int y = wy * WSZ + q / WSZ, xx = wx * WSZ + q % WSZ;
        aout[((size_t)bl * NPIX + y * WWI + xx) * CC + n * HD + d] = s;
    }
}

// ---------------------------------------------------------------------------
extern "C" void kernel_launch(void* const* d_in, const int* in_sizes, int n_in,
                              void* d_out, int out_size, void* d_ws, size_t ws_size,
                              hipStream_t stream) {
    (void)in_sizes; (void)n_in; (void)out_size; (void)ws_size;
    const float* x     = (const float*)d_in[0];
    const float* qkv_w = (const float*)d_in[1];
    const float* tw    = (const float*)d_in[2];
    const float* tb    = (const float*)d_in[3];
    const float* pw    = (const float*)d_in[4];
    const float* pb    = (const float*)d_in[5];
    const float* rph   = (const float*)d_in[6];
    const float* rpw   = (const float*)d_in[7];
    float* out = (float*)d_out;

    // ws layout (chunked; peak ~82 MB):
    float* ws   = (float*)d_ws;
    float* qkv  = ws;                                   // MCH*576       (57.8 MB)
    float* aout = qkv + (size_t)MCH * QKV_N;            // MCH*192       (19.3 MB)
    float* grid = aout + (size_t)MCH * CC;              // 48*112*112*2  ( 4.8 MB)

    // K2 once: pooled/transform/affine/grid for all batches
    pool_grid<<<dim3(BB * WN * WN), 64, 0, stream>>>(x, tw, tb, grid);

    for (int b0 = 0; b0 < BB; b0 += NB_CH) {
        const float* xc  = x   + (size_t)b0 * NPIX * CC;
        float*       oc  = out + (size_t)b0 * NPIX * CC;
        // K1: qkv_chunk = x_chunk @ qkv_w^T   (M=25088, N=576, K=192)
        gemm_mfma<<<dim3(QKV_N / 64, MCH / 128), 256, 0, stream>>>(
            xc, qkv_w, nullptr, qkv, MCH, QKV_N, CC);
        // K3: fused window attention for this chunk
        attn_win<<<dim3(NB_CH * WN * WN * NH), 256, 0, stream>>>(
            qkv, grid, rph, rpw, aout, b0);
        // K4: out_chunk = aout @ proj_w^T + proj_b  (M=25088, N=192, K=192)
        gemm_mfma<<<dim3(CC / 64, MCH / 128), 256, 0, stream>>>(
            aout, pw, pb, oc, MCH, CC, CC);
    }
}